// Round 12
// baseline (185.135 us; speedup 1.0000x reference)
//
#include <hip/hip_runtime.h>
#include <hip/hip_bf16.h>

#define B_  4
#define S_  1024
#define E_  256
#define H_  32
#define NQ_ 8
#define FF_ 1024
#define M_  (B_*S_)   // 4096 tokens
#define QS  0.5100880289202462f   // log2(e)/sqrt(8)
#define VSTRIDE 1036              // V^T row stride in shorts

typedef __attribute__((ext_vector_type(8))) short bf16x8;
typedef __attribute__((ext_vector_type(4))) short short4v;
typedef __attribute__((ext_vector_type(4))) float f32x4;

#if __has_builtin(__builtin_amdgcn_exp2f)
#define EXP2 __builtin_amdgcn_exp2f
#else
#define EXP2 exp2f
#endif

__device__ inline short f2bf(float f) {
    union { float f; unsigned u; } v; v.f = f;
    unsigned r = (v.u + 0x7fff + ((v.u >> 16) & 1)) >> 16;   // RNE
    return (short)r;
}

__device__ inline float bf2f(ushort u_) {
    union { unsigned u; float f; } c; c.u = ((unsigned)u_) << 16; return c.f;
}

__device__ inline unsigned pk2(float a, float b) {
    __hip_bfloat162 h = __float22bfloat162_rn(make_float2(a, b));
    union { __hip_bfloat162 h; unsigned u; } c; c.h = h;
    return c.u;
}

// ================= D0: qout = cos(x + theta[e%8]) -> bf16 =================
__global__ __launch_bounds__(256) void qout_kernel(const float* __restrict__ x,
                                                   const float* __restrict__ theta,
                                                   ushort* __restrict__ qout) {
    int i = blockIdx.x * 256 + threadIdx.x;          // one per 8 elements
    float4 a = ((const float4*)x)[i * 2];
    float4 b = ((const float4*)x)[i * 2 + 1];
    bf16x8 o;
    o[0] = f2bf(__cosf(a.x + theta[0]));
    o[1] = f2bf(__cosf(a.y + theta[1]));
    o[2] = f2bf(__cosf(a.z + theta[2]));
    o[3] = f2bf(__cosf(a.w + theta[3]));
    o[4] = f2bf(__cosf(b.x + theta[4]));
    o[5] = f2bf(__cosf(b.y + theta[5]));
    o[6] = f2bf(__cosf(b.z + theta[6]));
    o[7] = f2bf(__cosf(b.w + theta[7]));
    *(bf16x8*)(qout + (size_t)i * 8) = o;
}

// ================= D1: qkv GEMM (bf16 A) + weff MFMA + beff + w2/w1 conv =================
// [0,384) qkv gemm; [384,392) weff; [392,648) beff; [648,904) w2 conv; [904,912) w1 conv
__global__ __launch_bounds__(256) void d1_kernel(
        const ushort* __restrict__ qout, const float* __restrict__ w_in,
        const float* __restrict__ b_in,
        const float* __restrict__ w_out, const float* __restrict__ w_comb,
        const float* __restrict__ b_out, const float* __restrict__ b_comb,
        const float* __restrict__ w2, const float* __restrict__ w1,
        ushort* __restrict__ qkv_bf, ushort* __restrict__ weff_bf,
        float* __restrict__ beff, ushort* __restrict__ w2_bf,
        ushort* __restrict__ w1_bf) {
    __shared__ ushort As[128 * 64];
    __shared__ ushort Bs[64 * 64];
    __shared__ float red[4];
    int bid = blockIdx.x, tid = threadIdx.x;

    if (bid >= 392) {
        if (bid < 648) {                     // beff
            int i = bid - 392;
            float p = w_comb[(size_t)i * 256 + tid] * b_out[tid];
#pragma unroll
            for (int o = 32; o > 0; o >>= 1) p += __shfl_xor(p, o);
            if ((tid & 63) == 0) red[tid >> 6] = p;
            __syncthreads();
            if (tid == 0) beff[i] = red[0] + red[1] + red[2] + red[3] + b_comb[i];
        } else if (bid < 904) {              // w2 -> bf16
            int i = (bid - 648) * 256 + tid;
            float4 v = ((const float4*)w2)[i];
            short4v o = {f2bf(v.x), f2bf(v.y), f2bf(v.z), f2bf(v.w)};
            ((short4v*)w2_bf)[i] = o;
        } else {                             // w1 -> bf16  (8192 float4s)
            int i = (bid - 904) * 256 + tid;
            float4 v = ((const float4*)w1)[i];
            short4v o = {f2bf(v.x), f2bf(v.y), f2bf(v.z), f2bf(v.w)};
            ((short4v*)w1_bf)[i] = o;
        }
        return;
    }

    bool isW = bid >= 384;
    int bm, bn;
    if (!isW) { bm = (bid / 12) * 128; bn = (bid % 12) * 64; }
    else      { int t = bid - 384; bm = (t >> 2) * 128; bn = (t & 3) * 64; }

    int w = tid >> 6, l = tid & 63, lq = l & 15, hi = l >> 4;
    int wm = w & 1, wn = w >> 1;
    f32x4 acc[4][2] = {};
    int srow = tid >> 3;
    int sk = (tid & 7) * 8;
    float wscale = isW ? 1.f : ((bn < 256) ? QS : 1.f);

    for (int k0 = 0; k0 < 256; k0 += 64) {
        __syncthreads();
        if (!isW) {
#pragma unroll
            for (int it = 0; it < 4; ++it) {
                int row = it * 32 + srow;
                bf16x8 v = *(const bf16x8*)(qout + (size_t)(bm + row) * 256 + k0 + sk);
                *(bf16x8*)((char*)As + row * 128 + ((sk * 2) ^ ((row & 7) << 4))) = v;
            }
#pragma unroll
            for (int it = 0; it < 2; ++it) {
                int row = it * 32 + srow;
                const float* wp = w_in + (size_t)(bn + row) * 256 + k0 + sk;
                float4 a = *(const float4*)wp;
                float4 b = *(const float4*)(wp + 4);
                bf16x8 o;
                o[0] = f2bf(a.x * wscale); o[1] = f2bf(a.y * wscale);
                o[2] = f2bf(a.z * wscale); o[3] = f2bf(a.w * wscale);
                o[4] = f2bf(b.x * wscale); o[5] = f2bf(b.y * wscale);
                o[6] = f2bf(b.z * wscale); o[7] = f2bf(b.w * wscale);
                *(bf16x8*)((char*)Bs + row * 128 + ((sk * 2) ^ ((row & 7) << 4))) = o;
            }
        } else {
#pragma unroll
            for (int it = 0; it < 4; ++it) {
                int row = it * 32 + srow;
                const float* wp = w_comb + (size_t)(bm + row) * 256 + k0 + sk;
                float4 a = *(const float4*)wp;
                float4 b = *(const float4*)(wp + 4);
                bf16x8 o;
                o[0] = f2bf(a.x); o[1] = f2bf(a.y); o[2] = f2bf(a.z); o[3] = f2bf(a.w);
                o[4] = f2bf(b.x); o[5] = f2bf(b.y); o[6] = f2bf(b.z); o[7] = f2bf(b.w);
                *(bf16x8*)((char*)As + row * 128 + ((sk * 2) ^ ((row & 7) << 4))) = o;
            }
            int nl = tid & 63, kg = tid >> 6;
#pragma unroll
            for (int kk = 0; kk < 16; ++kk) {
                int kb = (kg * 16 + kk) * 2;
                float v = w_out[(size_t)(k0 + kg * 16 + kk) * 256 + bn + nl];
                *(ushort*)((char*)Bs + nl * 128 + (kb ^ ((nl & 7) << 4))) = (ushort)f2bf(v);
            }
        }
        __syncthreads();
#pragma unroll
        for (int kk = 0; kk < 2; ++kk) {
            bf16x8 af[4], bfr[2];
#pragma unroll
            for (int mf = 0; mf < 4; ++mf) {
                int row = wm * 64 + mf * 16 + lq;
                af[mf] = *(const bf16x8*)((const char*)As + row * 128 +
                                          ((kk * 64 + hi * 16) ^ ((row & 7) << 4)));
            }
#pragma unroll
            for (int nf = 0; nf < 2; ++nf) {
                int row = wn * 32 + nf * 16 + lq;
                bfr[nf] = *(const bf16x8*)((const char*)Bs + row * 128 +
                                           ((kk * 64 + hi * 16) ^ ((row & 7) << 4)));
            }
#pragma unroll
            for (int mf = 0; mf < 4; ++mf)
#pragma unroll
                for (int nf = 0; nf < 2; ++nf)
                    acc[mf][nf] = __builtin_amdgcn_mfma_f32_16x16x32_bf16(af[mf], bfr[nf], acc[mf][nf], 0, 0, 0);
        }
    }
    ushort* Cp = isW ? weff_bf : qkv_bf;
    int Nd = isW ? 256 : 768;
#pragma unroll
    for (int mf = 0; mf < 4; ++mf)
#pragma unroll
        for (int nf = 0; nf < 2; ++nf) {
            int n = bn + wn * 32 + nf * 16 + lq;
            float bv = isW ? 0.f : b_in[n] * wscale;
#pragma unroll
            for (int r = 0; r < 4; ++r) {
                int m = bm + wm * 64 + mf * 16 + hi * 4 + r;
                Cp[(size_t)m * Nd + n] = (ushort)f2bf(acc[mf][nf][r] + bv);
            }
        }
}

// ================= D2: MFMA flash attention (zero-shuffle PV, K in LDS, setprio) =================
__global__ __launch_bounds__(256, 4) void attn_mfma_kernel(const ushort* __restrict__ qkv,
                                                           ushort* __restrict__ ctx) {
    __shared__ ushort ks[S_ * 8];              // 16 KB, linear
    __shared__ ushort vt[9 * VSTRIDE + 4];     // 18.7 KB, permuted
    int qt = blockIdx.x, h = blockIdx.y, b = blockIdx.z;
    int tid = threadIdx.x;
    const ushort* base = qkv + (size_t)b * S_ * (3 * E_) + h * 8;

    for (int i = tid; i < S_; i += 256) {
        const ushort* rp = base + (size_t)i * (3 * E_);
        bf16x8 kv = *(const bf16x8*)(rp + E_);
        bf16x8 vv = *(const bf16x8*)(rp + 2 * E_);
        *(bf16x8*)&ks[i * 8] = kv;
        int kf = (i >> 4) & 3, hh = (i >> 2) & 3, s = i & 3;
        int pv = (i & ~63) + ((kf >> 1) << 5) + (hh << 3) + ((kf & 1) << 2) + s;
#pragma unroll
        for (int d = 0; d < 8; ++d) vt[d * VSTRIDE + pv] = vv[d];
        vt[8 * VSTRIDE + pv] = 0x3F80;
    }
    __syncthreads();

    int w = tid >> 6, l = tid & 63, lq = l & 15, g = l >> 4;

    bf16x8 qfrag[2];
#pragma unroll
    for (int qf = 0; qf < 2; ++qf) {
        bf16x8 qv = {};
        if (g == 0)
            qv = *(const bf16x8*)(base + (size_t)(qt * 128 + w * 32 + qf * 16 + lq) * (3 * E_));
        qfrag[qf] = qv;
    }

    f32x4 ctxa[2] = {{0.f,0.f,0.f,0.f},{0.f,0.f,0.f,0.f}};
    const f32x4 zf = {0.f, 0.f, 0.f, 0.f};

#pragma unroll 2
    for (int kt = 0; kt < 16; ++kt) {
        bf16x8 kfrag[4];
#pragma unroll
        for (int kf = 0; kf < 4; ++kf) {
            bf16x8 kv = {};
            if (g == 0) kv = *(bf16x8*)&ks[(kt * 64 + kf * 16 + lq) * 8];
            kfrag[kf] = kv;
        }
        bf16x8 vf0 = *(bf16x8*)&vt[lq * VSTRIDE + kt * 64 + g * 8];
        bf16x8 vf1 = *(bf16x8*)&vt[lq * VSTRIDE + kt * 64 + 32 + g * 8];
        __builtin_amdgcn_s_setprio(1);
#pragma unroll
        for (int qf = 0; qf < 2; ++qf) {
            f32x4 st[4];
#pragma unroll
            for (int kf = 0; kf < 4; ++kf)
                st[kf] = __builtin_amdgcn_mfma_f32_16x16x32_bf16(kfrag[kf], qfrag[qf], zf, 0, 0, 0);
            union { unsigned u[4]; bf16x8 v; } p0, p1;
            p0.u[0] = pk2(EXP2(st[0][0]), EXP2(st[0][1]));
            p0.u[1] = pk2(EXP2(st[0][2]), EXP2(st[0][3]));
            p0.u[2] = pk2(EXP2(st[1][0]), EXP2(st[1][1]));
            p0.u[3] = pk2(EXP2(st[1][2]), EXP2(st[1][3]));
            p1.u[0] = pk2(EXP2(st[2][0]), EXP2(st[2][1]));
            p1.u[1] = pk2(EXP2(st[2][2]), EXP2(st[2][3]));
            p1.u[2] = pk2(EXP2(st[3][0]), EXP2(st[3][1]));
            p1.u[3] = pk2(EXP2(st[3][2]), EXP2(st[3][3]));
            ctxa[qf] = __builtin_amdgcn_mfma_f32_16x16x32_bf16(p0.v, vf0, ctxa[qf], 0, 0, 0);
            ctxa[qf] = __builtin_amdgcn_mfma_f32_16x16x32_bf16(p1.v, vf1, ctxa[qf], 0, 0, 0);
        }
        __builtin_amdgcn_s_setprio(0);
    }

#pragma unroll
    for (int qf = 0; qf < 2; ++qf) {
        int src = (l & 48) + 8;
        float s0 = __shfl(ctxa[qf][0], src);
        float s1 = __shfl(ctxa[qf][1], src);
        float s2 = __shfl(ctxa[qf][2], src);
        float s3 = __shfl(ctxa[qf][3], src);
        if (lq < 8) {
            float i0 = __builtin_amdgcn_rcpf(s0);
            float i1 = __builtin_amdgcn_rcpf(s1);
            float i2 = __builtin_amdgcn_rcpf(s2);
            float i3 = __builtin_amdgcn_rcpf(s3);
            int tok = b * S_ + qt * 128 + w * 32 + qf * 16 + g * 4;
            ushort* cp = ctx + (size_t)tok * E_ + h * 8 + lq;
            cp[0]      = (ushort)f2bf(ctxa[qf][0] * i0);
            cp[E_]     = (ushort)f2bf(ctxa[qf][1] * i1);
            cp[2 * E_] = (ushort)f2bf(ctxa[qf][2] * i2);
            cp[3 * E_] = (ushort)f2bf(ctxa[qf][3] * i3);
        }
    }
}

// ================= D34: ctx GEMM + LN1 + qf + t + ffn2 GEMM + LN2 -> out =================
// BM=16, 256 threads (4 waves, wave = 16x64), grid 256. GEMM operands streamed
// directly from global (L2) in MFMA fragment layout; h fp32 + t bf16 (swizzled) in LDS.
__global__ __launch_bounds__(256) void d34_kernel(
        const ushort* __restrict__ ctx, const ushort* __restrict__ weff,
        const float* __restrict__ beff, const float* __restrict__ x,
        const float* __restrict__ g1, const float* __restrict__ be1,
        const float* __restrict__ w_ip, const float* __restrict__ b_ip,
        const float* __restrict__ theta_ffn,
        const ushort* __restrict__ w1b, const float* __restrict__ b1,
        const ushort* __restrict__ w2b, const float* __restrict__ b2,
        const float* __restrict__ g2, const float* __restrict__ be2,
        float* __restrict__ out) {
    __shared__ float hs[16 * 260];       // 16.6 KB fp32 h
    __shared__ float qfl[16 * 8];
    __shared__ ushort ts[16 * 1024];     // 32 KB swizzled t
    __shared__ float red[2][16][4];
    int tid = threadIdx.x;
    int bm = blockIdx.x * 16;
    int wn = tid >> 6, l = tid & 63, lq = l & 15, hi = l >> 4;

    // ---- GEMM1: ctx @ weff^T, direct global fragments ----
    f32x4 acc[4] = {};
#pragma unroll
    for (int k0 = 0; k0 < 256; k0 += 64) {
#pragma unroll
        for (int kk = 0; kk < 2; ++kk) {
            bf16x8 af = *(const bf16x8*)(ctx + (size_t)(bm + lq) * 256 + k0 + kk * 32 + hi * 8);
#pragma unroll
            for (int nf = 0; nf < 4; ++nf) {
                int rb = wn * 64 + nf * 16 + lq;
                bf16x8 bf_ = *(const bf16x8*)(weff + (size_t)rb * 256 + k0 + kk * 32 + hi * 8);
                acc[nf] = __builtin_amdgcn_mfma_f32_16x16x32_bf16(af, bf_, acc[nf], 0, 0, 0);
            }
        }
    }

    // ---- bias + residual + LN1 -> hs ----
    float vv[4][4];
    float rs[4] = {}, rq[4] = {};
#pragma unroll
    for (int nf = 0; nf < 4; ++nf) {
        int n = wn * 64 + nf * 16 + lq;
        float bv = beff[n];
#pragma unroll
        for (int r = 0; r < 4; ++r) {
            int m = bm + hi * 4 + r;
            float val = acc[nf][r] + bv + x[(size_t)m * 256 + n];
            vv[nf][r] = val;
            rs[r] += val;
            rq[r] += val * val;
        }
    }
#pragma unroll
    for (int o = 1; o < 16; o <<= 1)
#pragma unroll
        for (int r = 0; r < 4; ++r) {
            rs[r] += __shfl_xor(rs[r], o);
            rq[r] += __shfl_xor(rq[r], o);
        }
    if (lq == 0) {
#pragma unroll
        for (int r = 0; r < 4; ++r) {
            red[0][hi * 4 + r][wn] = rs[r];
            red[1][hi * 4 + r][wn] = rq[r];
        }
    }
    __syncthreads();
#pragma unroll
    for (int r = 0; r < 4; ++r) {
        int row = hi * 4 + r;
        float st_ = red[0][row][0] + red[0][row][1] + red[0][row][2] + red[0][row][3];
        float sq_ = red[1][row][0] + red[1][row][1] + red[1][row][2] + red[1][row][3];
        float mu = st_ * (1.f / 256.f);
        float var = sq_ * (1.f / 256.f) - mu * mu;
        rs[r] = mu;
        rq[r] = rsqrtf(var + 1e-5f);
    }
#pragma unroll
    for (int nf = 0; nf < 4; ++nf) {
        int n = wn * 64 + nf * 16 + lq;
        float gn = g1[n], bn_ = be1[n];
#pragma unroll
        for (int r = 0; r < 4; ++r) {
            int row = hi * 4 + r;
            hs[row * 260 + n] = (vv[nf][r] - rs[r]) * rq[r] * gn + bn_;
        }
    }
    __syncthreads();

    // ---- qf: threads 0..127 -> (tok, wire) ----
    if (tid < 128) {
        int tok = tid >> 3, wq = tid & 7;
        const float* wip = w_ip + wq * 256;
        float pr = 0.f;
#pragma unroll
        for (int c = 0; c < 64; ++c) {
            float4 hv = *(const float4*)&hs[tok * 260 + c * 4];
            float4 wv = *(const float4*)(wip + c * 4);
            pr += hv.x * wv.x + hv.y * wv.y + hv.z * wv.z + hv.w * wv.w;
        }
        qfl[tok * 8 + wq] = __cosf(theta_ffn[wq]) * __cosf(pr + b_ip[wq]);
    }
    __syncthreads();

    // ---- t = relu(qf @ w1^T + b1) -> ts (swizzled bf16), w1 from bf16 ----
    {
        int row = tid & 15, fb = tid >> 4;
        float q[8];
#pragma unroll
        for (int k = 0; k < 8; ++k) q[k] = qfl[row * 8 + k];
#pragma unroll
        for (int j8 = 0; j8 < 8; ++j8) {
            int f0 = fb * 64 + j8 * 8;
            bf16x8 o;
#pragma unroll
            for (int j = 0; j < 8; ++j) {
                bf16x8 wv = *(const bf16x8*)(w1b + (size_t)(f0 + j) * 8);
                float s = b1[f0 + j];
#pragma unroll
                for (int k = 0; k < 8; ++k) s += q[k] * bf2f((ushort)wv[k]);
                o[j] = f2bf(fmaxf(s, 0.f));
            }
            *(bf16x8*)((char*)ts + row * 2048 + ((f0 * 2) ^ ((row & 7) << 4))) = o;
        }
    }
    __syncthreads();

    // ---- GEMM2: t @ w2^T, A from swizzled LDS, B direct global ----
    f32x4 acc2[4] = {};
#pragma unroll 4
    for (int k0 = 0; k0 < 1024; k0 += 64) {
#pragma unroll
        for (int kk = 0; kk < 2; ++kk) {
            bf16x8 af = *(const bf16x8*)((const char*)ts + lq * 2048 +
                                         ((k0 * 2 + kk * 64 + hi * 16) ^ ((lq & 7) << 4)));
#pragma unroll
            for (int nf = 0; nf < 4; ++nf) {
                int rb = wn * 64 + nf * 16 + lq;
                bf16x8 bf_ = *(const bf16x8*)(w2b + (size_t)rb * 1024 + k0 + kk * 32 + hi * 8);
                acc2[nf] = __builtin_amdgcn_mfma_f32_16x16x32_bf16(af, bf_, acc2[nf], 0, 0, 0);
            }
        }
    }

    // ---- bias + residual(hs) + LN2 -> out ----
    float rs2[4] = {}, rq2[4] = {};
#pragma unroll
    for (int nf = 0; nf < 4; ++nf) {
        int n = wn * 64 + nf * 16 + lq;
        float bv = b2[n];
#pragma unroll
        for (int r = 0; r < 4; ++r) {
            int row = hi * 4 + r;
            float val = acc2[nf][r] + bv + hs[row * 260 + n];
            vv[nf][r] = val;
            rs2[r] += val;
            rq2[r] += val * val;
        }
    }
#pragma unroll
    for (int o = 1; o < 16; o <<= 1)
#pragma unroll
        for (int r = 0; r < 4; ++r) {
            rs2[r] += __shfl_xor(rs2[r], o);
            rq2[r] += __shfl_xor(rq2[r], o);
        }
    __syncthreads();   // red reuse
    if (lq == 0) {
#pragma unroll
        for (int r = 0; r < 4; ++r) {
            red[0][hi * 4 + r][wn] = rs2[r];
            red[1][hi * 4 + r][wn] = rq2[r];
        }
    }
    __syncthreads();
#pragma unroll
    for (int r = 0; r < 4; ++r) {
        int row = hi * 4 + r;
        float st_ = red[0][row][0] + red[0][row][1] + red[0][row][2] + red[0][row][3];
        float sq_ = red[1][row][0] + red[1][row][1] + red[1][row][2] + red[1][row][3];
        float mu = st_ * (1.f / 256.f);
        float var = sq_ * (1.f / 256.f) - mu * mu;
        rs2[r] = mu;
        rq2[r] = rsqrtf(var + 1e-5f);
    }
#pragma unroll
    for (int nf = 0; nf < 4; ++nf) {
        int n = wn * 64 + nf * 16 + lq;
        float gn = g2[n], bn_ = be2[n];
#pragma unroll
        for (int r = 0; r < 4; ++r) {
            int row = hi * 4 + r;
            out[(size_t)(bm + row) * 256 + n] =
                (vv[nf][r] - rs2[r]) * rq2[r] * gn + bn_;
        }
    }
}

extern "C" void kernel_launch(void* const* d_in, const int* in_sizes, int n_in,
                              void* d_out, int out_size, void* d_ws, size_t ws_size,
                              hipStream_t stream) {
    const float* x          = (const float*)d_in[0];
    const float* theta_attn = (const float*)d_in[1];
    const float* w_in       = (const float*)d_in[2];
    const float* b_in       = (const float*)d_in[3];
    const float* w_out      = (const float*)d_in[4];
    const float* b_out      = (const float*)d_in[5];
    const float* w_comb     = (const float*)d_in[6];
    const float* b_comb     = (const float*)d_in[7];
    const float* g1         = (const float*)d_in[8];
    const float* be1        = (const float*)d_in[9];
    const float* g2         = (const float*)d_in[10];
    const float* be2        = (const float*)d_in[11];
    const float* w_ip       = (const float*)d_in[12];
    const float* b_ip       = (const float*)d_in[13];
    const float* theta_ffn  = (const float*)d_in[14];
    const float* w1         = (const float*)d_in[15];
    const float* b1         = (const float*)d_in[16];
    const float* w2         = (const float*)d_in[17];
    const float* b2         = (const float*)d_in[18];
    float* out = (float*)d_out;

    char* wsb = (char*)d_ws;
    ushort* qkv_bf  = (ushort*)(wsb);                         // [0, 6MB)
    ushort* ctx_bf  = (ushort*)(wsb + (6u << 20));            // [6, 8MB)
    ushort* weff_bf = (ushort*)(wsb + (8u << 20));            // 128KB
    ushort* w2_bf   = (ushort*)(wsb + (8u << 20) + 131072);   // 512KB
    float*  beff    = (float*)(wsb + (9u << 20));             // 1KB
    ushort* w1_bf   = (ushort*)(wsb + (9u << 20) + 4096);     // 16KB
    ushort* qout_bf = (ushort*)(wsb + (10u << 20));           // 2MB

    qout_kernel<<<512, 256, 0, stream>>>(x, theta_attn, qout_bf);
    d1_kernel<<<912, 256, 0, stream>>>(qout_bf, w_in, b_in, w_out, w_comb,
                                       b_out, b_comb, w2, w1,
                                       qkv_bf, weff_bf, beff, w2_bf, w1_bf);
    attn_mfma_kernel<<<dim3(S_ / 128, H_, B_), 256, 0, stream>>>(qkv_bf, ctx_bf);
    d34_kernel<<<M_ / 16, 256, 0, stream>>>(ctx_bf, weff_bf, beff, x, g1, be1,
                                            w_ip, b_ip, theta_ffn, w1_bf, b1,
                                            w2_bf, b2, g2, be2, out);
}

// Round 13
// 179.305 us; speedup vs baseline: 1.0325x; 1.0325x over previous
//
#include <hip/hip_runtime.h>
#include <hip/hip_bf16.h>

#define B_  4
#define S_  1024
#define E_  256
#define H_  32
#define NQ_ 8
#define FF_ 1024
#define M_  (B_*S_)   // 4096 tokens
#define QS  0.5100880289202462f   // log2(e)/sqrt(8)
#define VSTRIDE 1036              // V^T row stride in shorts

typedef __attribute__((ext_vector_type(8))) short bf16x8;
typedef __attribute__((ext_vector_type(4))) short short4v;
typedef __attribute__((ext_vector_type(4))) float f32x4;

#if __has_builtin(__builtin_amdgcn_exp2f)
#define EXP2 __builtin_amdgcn_exp2f
#else
#define EXP2 exp2f
#endif

__device__ inline short f2bf(float f) {
    union { float f; unsigned u; } v; v.f = f;
    unsigned r = (v.u + 0x7fff + ((v.u >> 16) & 1)) >> 16;   // RNE
    return (short)r;
}

__device__ inline float bf2f(ushort u_) {
    union { unsigned u; float f; } c; c.u = ((unsigned)u_) << 16; return c.f;
}

__device__ inline unsigned pk2(float a, float b) {
    __hip_bfloat162 h = __float22bfloat162_rn(make_float2(a, b));
    union { __hip_bfloat162 h; unsigned u; } c; c.h = h;
    return c.u;
}

// ================= D1: qkv GEMM (fused cos) + weff MFMA + beff + w2 conv =================
__global__ __launch_bounds__(256) void d1_kernel(
        const float* __restrict__ x, const float* __restrict__ theta_attn,
        const float* __restrict__ w_in, const float* __restrict__ b_in,
        const float* __restrict__ w_out, const float* __restrict__ w_comb,
        const float* __restrict__ b_out, const float* __restrict__ b_comb,
        const float* __restrict__ w2,
        ushort* __restrict__ qkv_bf, ushort* __restrict__ weff_bf,
        float* __restrict__ beff, ushort* __restrict__ w2_bf) {
    __shared__ ushort As[128 * 64];
    __shared__ ushort Bs[64 * 64];
    __shared__ float red[4];
    int bid = blockIdx.x, tid = threadIdx.x;

    if (bid >= 392) {
        if (bid < 648) {                     // beff
            int i = bid - 392;
            float p = w_comb[(size_t)i * 256 + tid] * b_out[tid];
#pragma unroll
            for (int o = 32; o > 0; o >>= 1) p += __shfl_xor(p, o);
            if ((tid & 63) == 0) red[tid >> 6] = p;
            __syncthreads();
            if (tid == 0) beff[i] = red[0] + red[1] + red[2] + red[3] + b_comb[i];
        } else {                             // w2 -> bf16
            int i = (bid - 648) * 256 + tid;
            float4 v = ((const float4*)w2)[i];
            short4v o = {f2bf(v.x), f2bf(v.y), f2bf(v.z), f2bf(v.w)};
            ((short4v*)w2_bf)[i] = o;
        }
        return;
    }

    bool isW = bid >= 384;
    int bm, bn;
    if (!isW) { bm = (bid / 12) * 128; bn = (bid % 12) * 64; }
    else      { int t = bid - 384; bm = (t >> 2) * 128; bn = (t & 3) * 64; }

    int w = tid >> 6, l = tid & 63, lq = l & 15, hi = l >> 4;
    int wm = w & 1, wn = w >> 1;
    f32x4 acc[4][2] = {};
    int srow = tid >> 3;
    int sk = (tid & 7) * 8;
    float wscale = isW ? 1.f : ((bn < 256) ? QS : 1.f);
    float th[8];
    if (!isW) {
#pragma unroll
        for (int j = 0; j < 8; ++j) th[j] = theta_attn[j];
    }

    for (int k0 = 0; k0 < 256; k0 += 64) {
        __syncthreads();
        if (!isW) {
#pragma unroll
            for (int it = 0; it < 4; ++it) {
                int row = it * 32 + srow;
                const float* xp = x + (size_t)(bm + row) * 256 + k0 + sk;
                float4 a = *(const float4*)xp;
                float4 b = *(const float4*)(xp + 4);
                bf16x8 o;
                o[0] = f2bf(__cosf(a.x + th[0]));
                o[1] = f2bf(__cosf(a.y + th[1]));
                o[2] = f2bf(__cosf(a.z + th[2]));
                o[3] = f2bf(__cosf(a.w + th[3]));
                o[4] = f2bf(__cosf(b.x + th[4]));
                o[5] = f2bf(__cosf(b.y + th[5]));
                o[6] = f2bf(__cosf(b.z + th[6]));
                o[7] = f2bf(__cosf(b.w + th[7]));
                *(bf16x8*)((char*)As + row * 128 + ((sk * 2) ^ ((row & 7) << 4))) = o;
            }
#pragma unroll
            for (int it = 0; it < 2; ++it) {
                int row = it * 32 + srow;
                const float* wp = w_in + (size_t)(bn + row) * 256 + k0 + sk;
                float4 a = *(const float4*)wp;
                float4 b = *(const float4*)(wp + 4);
                bf16x8 o;
                o[0] = f2bf(a.x * wscale); o[1] = f2bf(a.y * wscale);
                o[2] = f2bf(a.z * wscale); o[3] = f2bf(a.w * wscale);
                o[4] = f2bf(b.x * wscale); o[5] = f2bf(b.y * wscale);
                o[6] = f2bf(b.z * wscale); o[7] = f2bf(b.w * wscale);
                *(bf16x8*)((char*)Bs + row * 128 + ((sk * 2) ^ ((row & 7) << 4))) = o;
            }
        } else {
#pragma unroll
            for (int it = 0; it < 4; ++it) {
                int row = it * 32 + srow;
                const float* wp = w_comb + (size_t)(bm + row) * 256 + k0 + sk;
                float4 a = *(const float4*)wp;
                float4 b = *(const float4*)(wp + 4);
                bf16x8 o;
                o[0] = f2bf(a.x); o[1] = f2bf(a.y); o[2] = f2bf(a.z); o[3] = f2bf(a.w);
                o[4] = f2bf(b.x); o[5] = f2bf(b.y); o[6] = f2bf(b.z); o[7] = f2bf(b.w);
                *(bf16x8*)((char*)As + row * 128 + ((sk * 2) ^ ((row & 7) << 4))) = o;
            }
            int nl = tid & 63, kg = tid >> 6;
#pragma unroll
            for (int kk = 0; kk < 16; ++kk) {
                int kb = (kg * 16 + kk) * 2;
                float v = w_out[(size_t)(k0 + kg * 16 + kk) * 256 + bn + nl];
                *(ushort*)((char*)Bs + nl * 128 + (kb ^ ((nl & 7) << 4))) = (ushort)f2bf(v);
            }
        }
        __syncthreads();
#pragma unroll
        for (int kk = 0; kk < 2; ++kk) {
            bf16x8 af[4], bfr[2];
#pragma unroll
            for (int mf = 0; mf < 4; ++mf) {
                int row = wm * 64 + mf * 16 + lq;
                af[mf] = *(const bf16x8*)((const char*)As + row * 128 +
                                          ((kk * 64 + hi * 16) ^ ((row & 7) << 4)));
            }
#pragma unroll
            for (int nf = 0; nf < 2; ++nf) {
                int row = wn * 32 + nf * 16 + lq;
                bfr[nf] = *(const bf16x8*)((const char*)Bs + row * 128 +
                                           ((kk * 64 + hi * 16) ^ ((row & 7) << 4)));
            }
#pragma unroll
            for (int mf = 0; mf < 4; ++mf)
#pragma unroll
                for (int nf = 0; nf < 2; ++nf)
                    acc[mf][nf] = __builtin_amdgcn_mfma_f32_16x16x32_bf16(af[mf], bfr[nf], acc[mf][nf], 0, 0, 0);
        }
    }
    ushort* Cp = isW ? weff_bf : qkv_bf;
    int Nd = isW ? 256 : 768;
#pragma unroll
    for (int mf = 0; mf < 4; ++mf)
#pragma unroll
        for (int nf = 0; nf < 2; ++nf) {
            int n = bn + wn * 32 + nf * 16 + lq;
            float bv = isW ? 0.f : b_in[n] * wscale;
#pragma unroll
            for (int r = 0; r < 4; ++r) {
                int m = bm + wm * 64 + mf * 16 + hi * 4 + r;
                Cp[(size_t)m * Nd + n] = (ushort)f2bf(acc[mf][nf][r] + bv);
            }
        }
}

// ================= D2: MFMA flash attention, QBLK=256, 512 threads =================
// Per-wave structure identical to the 256-thread version (32 queries, 2 qfrags);
// 8 waves per block -> K/V staging amortized over 2x the queries (512 blocks total).
__global__ __launch_bounds__(512, 2) void attn_mfma_kernel(const ushort* __restrict__ qkv,
                                                           ushort* __restrict__ ctx) {
    __shared__ ushort ks[S_ * 8];              // 16 KB, linear
    __shared__ ushort vt[9 * VSTRIDE + 4];     // 18.7 KB, permuted
    int qt = blockIdx.x, h = blockIdx.y, b = blockIdx.z;   // qt in [0,4)
    int tid = threadIdx.x;                     // 512
    const ushort* base = qkv + (size_t)b * S_ * (3 * E_) + h * 8;

    for (int i = tid; i < S_; i += 512) {
        const ushort* rp = base + (size_t)i * (3 * E_);
        bf16x8 kv = *(const bf16x8*)(rp + E_);
        bf16x8 vv = *(const bf16x8*)(rp + 2 * E_);
        *(bf16x8*)&ks[i * 8] = kv;
        int kf = (i >> 4) & 3, hh = (i >> 2) & 3, s = i & 3;
        int pv = (i & ~63) + ((kf >> 1) << 5) + (hh << 3) + ((kf & 1) << 2) + s;
#pragma unroll
        for (int d = 0; d < 8; ++d) vt[d * VSTRIDE + pv] = vv[d];
        vt[8 * VSTRIDE + pv] = 0x3F80;
    }
    __syncthreads();

    int w = tid >> 6, l = tid & 63, lq = l & 15, g = l >> 4;   // w in [0,8)

    bf16x8 qfrag[2];
#pragma unroll
    for (int qf = 0; qf < 2; ++qf) {
        bf16x8 qv = {};
        if (g == 0)
            qv = *(const bf16x8*)(base + (size_t)(qt * 256 + w * 32 + qf * 16 + lq) * (3 * E_));
        qfrag[qf] = qv;
    }

    f32x4 ctxa[2] = {{0.f,0.f,0.f,0.f},{0.f,0.f,0.f,0.f}};
    const f32x4 zf = {0.f, 0.f, 0.f, 0.f};

#pragma unroll 2
    for (int kt = 0; kt < 16; ++kt) {
        bf16x8 kfrag[4];
#pragma unroll
        for (int kf = 0; kf < 4; ++kf) {
            bf16x8 kv = {};
            if (g == 0) kv = *(bf16x8*)&ks[(kt * 64 + kf * 16 + lq) * 8];
            kfrag[kf] = kv;
        }
        bf16x8 vf0 = *(bf16x8*)&vt[lq * VSTRIDE + kt * 64 + g * 8];
        bf16x8 vf1 = *(bf16x8*)&vt[lq * VSTRIDE + kt * 64 + 32 + g * 8];
        __builtin_amdgcn_s_setprio(1);
#pragma unroll
        for (int qf = 0; qf < 2; ++qf) {
            f32x4 st[4];
#pragma unroll
            for (int kf = 0; kf < 4; ++kf)
                st[kf] = __builtin_amdgcn_mfma_f32_16x16x32_bf16(kfrag[kf], qfrag[qf], zf, 0, 0, 0);
            union { unsigned u[4]; bf16x8 v; } p0, p1;
            p0.u[0] = pk2(EXP2(st[0][0]), EXP2(st[0][1]));
            p0.u[1] = pk2(EXP2(st[0][2]), EXP2(st[0][3]));
            p0.u[2] = pk2(EXP2(st[1][0]), EXP2(st[1][1]));
            p0.u[3] = pk2(EXP2(st[1][2]), EXP2(st[1][3]));
            p1.u[0] = pk2(EXP2(st[2][0]), EXP2(st[2][1]));
            p1.u[1] = pk2(EXP2(st[2][2]), EXP2(st[2][3]));
            p1.u[2] = pk2(EXP2(st[3][0]), EXP2(st[3][1]));
            p1.u[3] = pk2(EXP2(st[3][2]), EXP2(st[3][3]));
            ctxa[qf] = __builtin_amdgcn_mfma_f32_16x16x32_bf16(p0.v, vf0, ctxa[qf], 0, 0, 0);
            ctxa[qf] = __builtin_amdgcn_mfma_f32_16x16x32_bf16(p1.v, vf1, ctxa[qf], 0, 0, 0);
        }
        __builtin_amdgcn_s_setprio(0);
    }

#pragma unroll
    for (int qf = 0; qf < 2; ++qf) {
        int src = (l & 48) + 8;
        float s0 = __shfl(ctxa[qf][0], src);
        float s1 = __shfl(ctxa[qf][1], src);
        float s2 = __shfl(ctxa[qf][2], src);
        float s3 = __shfl(ctxa[qf][3], src);
        if (lq < 8) {
            float i0 = __builtin_amdgcn_rcpf(s0);
            float i1 = __builtin_amdgcn_rcpf(s1);
            float i2 = __builtin_amdgcn_rcpf(s2);
            float i3 = __builtin_amdgcn_rcpf(s3);
            int tok = b * S_ + qt * 256 + w * 32 + qf * 16 + g * 4;
            ushort* cp = ctx + (size_t)tok * E_ + h * 8 + lq;
            cp[0]      = (ushort)f2bf(ctxa[qf][0] * i0);
            cp[E_]     = (ushort)f2bf(ctxa[qf][1] * i1);
            cp[2 * E_] = (ushort)f2bf(ctxa[qf][2] * i2);
            cp[3 * E_] = (ushort)f2bf(ctxa[qf][3] * i3);
        }
    }
}

// ================= D34: ctx GEMM + LN1 + qf + t + ffn2 GEMM + LN2 -> out =================
// BM=16, 256 threads (4 waves, wave = 16x64), grid 256. GEMM operands streamed
// directly from global (L2) in MFMA fragment layout; h fp32 + t bf16 (swizzled) in LDS.
__global__ __launch_bounds__(256) void d34_kernel(
        const ushort* __restrict__ ctx, const ushort* __restrict__ weff,
        const float* __restrict__ beff, const float* __restrict__ x,
        const float* __restrict__ g1, const float* __restrict__ be1,
        const float* __restrict__ w_ip, const float* __restrict__ b_ip,
        const float* __restrict__ theta_ffn,
        const float* __restrict__ w1, const float* __restrict__ b1,
        const ushort* __restrict__ w2b, const float* __restrict__ b2,
        const float* __restrict__ g2, const float* __restrict__ be2,
        float* __restrict__ out) {
    __shared__ float hs[16 * 260];       // 16.6 KB fp32 h
    __shared__ float qfl[16 * 8];
    __shared__ ushort ts[16 * 1024];     // 32 KB swizzled t
    __shared__ float red[2][16][4];
    int tid = threadIdx.x;
    int bm = blockIdx.x * 16;
    int wn = tid >> 6, l = tid & 63, lq = l & 15, hi = l >> 4;

    // ---- GEMM1: ctx @ weff^T, direct global fragments ----
    f32x4 acc[4] = {};
#pragma unroll
    for (int k0 = 0; k0 < 256; k0 += 64) {
#pragma unroll
        for (int kk = 0; kk < 2; ++kk) {
            bf16x8 af = *(const bf16x8*)(ctx + (size_t)(bm + lq) * 256 + k0 + kk * 32 + hi * 8);
#pragma unroll
            for (int nf = 0; nf < 4; ++nf) {
                int rb = wn * 64 + nf * 16 + lq;
                bf16x8 bf_ = *(const bf16x8*)(weff + (size_t)rb * 256 + k0 + kk * 32 + hi * 8);
                acc[nf] = __builtin_amdgcn_mfma_f32_16x16x32_bf16(af, bf_, acc[nf], 0, 0, 0);
            }
        }
    }

    // ---- bias + residual + LN1 -> hs ----
    float vv[4][4];
    float rs[4] = {}, rq[4] = {};
#pragma unroll
    for (int nf = 0; nf < 4; ++nf) {
        int n = wn * 64 + nf * 16 + lq;
        float bv = beff[n];
#pragma unroll
        for (int r = 0; r < 4; ++r) {
            int m = bm + hi * 4 + r;
            float val = acc[nf][r] + bv + x[(size_t)m * 256 + n];
            vv[nf][r] = val;
            rs[r] += val;
            rq[r] += val * val;
        }
    }
#pragma unroll
    for (int o = 1; o < 16; o <<= 1)
#pragma unroll
        for (int r = 0; r < 4; ++r) {
            rs[r] += __shfl_xor(rs[r], o);
            rq[r] += __shfl_xor(rq[r], o);
        }
    if (lq == 0) {
#pragma unroll
        for (int r = 0; r < 4; ++r) {
            red[0][hi * 4 + r][wn] = rs[r];
            red[1][hi * 4 + r][wn] = rq[r];
        }
    }
    __syncthreads();
#pragma unroll
    for (int r = 0; r < 4; ++r) {
        int row = hi * 4 + r;
        float st_ = red[0][row][0] + red[0][row][1] + red[0][row][2] + red[0][row][3];
        float sq_ = red[1][row][0] + red[1][row][1] + red[1][row][2] + red[1][row][3];
        float mu = st_ * (1.f / 256.f);
        float var = sq_ * (1.f / 256.f) - mu * mu;
        rs[r] = mu;
        rq[r] = rsqrtf(var + 1e-5f);
    }
#pragma unroll
    for (int nf = 0; nf < 4; ++nf) {
        int n = wn * 64 + nf * 16 + lq;
        float gn = g1[n], bn_ = be1[n];
#pragma unroll
        for (int r = 0; r < 4; ++r) {
            int row = hi * 4 + r;
            hs[row * 260 + n] = (vv[nf][r] - rs[r]) * rq[r] * gn + bn_;
        }
    }
    __syncthreads();

    // ---- qf: threads 0..127 -> (tok, wire) ----
    if (tid < 128) {
        int tok = tid >> 3, wq = tid & 7;
        const float* wip = w_ip + wq * 256;
        float pr = 0.f;
#pragma unroll
        for (int c = 0; c < 64; ++c) {
            float4 hv = *(const float4*)&hs[tok * 260 + c * 4];
            float4 wv = *(const float4*)(wip + c * 4);
            pr += hv.x * wv.x + hv.y * wv.y + hv.z * wv.z + hv.w * wv.w;
        }
        qfl[tok * 8 + wq] = __cosf(theta_ffn[wq]) * __cosf(pr + b_ip[wq]);
    }
    __syncthreads();

    // ---- t = relu(qf @ w1^T + b1) -> ts (swizzled bf16) ----
    {
        int row = tid & 15, fb = tid >> 4;
        float q[8];
#pragma unroll
        for (int k = 0; k < 8; ++k) q[k] = qfl[row * 8 + k];
#pragma unroll
        for (int j8 = 0; j8 < 8; ++j8) {
            int f0 = fb * 64 + j8 * 8;
            bf16x8 o;
#pragma unroll
            for (int j = 0; j < 8; ++j) {
                const float* wp = w1 + (size_t)(f0 + j) * 8;
                float4 wa = *(const float4*)wp;
                float4 wb = *(const float4*)(wp + 4);
                float s = b1[f0 + j]
                        + q[0] * wa.x + q[1] * wa.y + q[2] * wa.z + q[3] * wa.w
                        + q[4] * wb.x + q[5] * wb.y + q[6] * wb.z + q[7] * wb.w;
                o[j] = f2bf(fmaxf(s, 0.f));
            }
            *(bf16x8*)((char*)ts + row * 2048 + ((f0 * 2) ^ ((row & 7) << 4))) = o;
        }
    }
    __syncthreads();

    // ---- GEMM2: t @ w2^T, A from swizzled LDS, B direct global ----
    f32x4 acc2[4] = {};
#pragma unroll 4
    for (int k0 = 0; k0 < 1024; k0 += 64) {
#pragma unroll
        for (int kk = 0; kk < 2; ++kk) {
            bf16x8 af = *(const bf16x8*)((const char*)ts + lq * 2048 +
                                         ((k0 * 2 + kk * 64 + hi * 16) ^ ((lq & 7) << 4)));
#pragma unroll
            for (int nf = 0; nf < 4; ++nf) {
                int rb = wn * 64 + nf * 16 + lq;
                bf16x8 bf_ = *(const bf16x8*)(w2b + (size_t)rb * 1024 + k0 + kk * 32 + hi * 8);
                acc2[nf] = __builtin_amdgcn_mfma_f32_16x16x32_bf16(af, bf_, acc2[nf], 0, 0, 0);
            }
        }
    }

    // ---- bias + residual(hs) + LN2 -> out ----
    float rs2[4] = {}, rq2[4] = {};
#pragma unroll
    for (int nf = 0; nf < 4; ++nf) {
        int n = wn * 64 + nf * 16 + lq;
        float bv = b2[n];
#pragma unroll
        for (int r = 0; r < 4; ++r) {
            int row = hi * 4 + r;
            float val = acc2[nf][r] + bv + hs[row * 260 + n];
            vv[nf][r] = val;
            rs2[r] += val;
            rq2[r] += val * val;
        }
    }
#pragma unroll
    for (int o = 1; o < 16; o <<= 1)
#pragma unroll
        for (int r = 0; r < 4; ++r) {
            rs2[r] += __shfl_xor(rs2[r], o);
            rq2[r] += __shfl_xor(rq2[r], o);
        }
    __syncthreads();   // red reuse
    if (lq == 0) {
#pragma unroll
        for (int r = 0; r < 4; ++r) {
            red[0][hi * 4 + r][wn] = rs2[r];
            red[1][hi * 4 + r][wn] = rq2[r];
        }
    }
    __syncthreads();
#pragma unroll
    for (int r = 0; r < 4; ++r) {
        int row = hi * 4 + r;
        float st_ = red[0][row][0] + red[0][row][1] + red[0][row][2] + red[0][row][3];
        float sq_ = red[1][row][0] + red[1][row][1] + red[1][row][2] + red[1][row][3];
        float mu = st_ * (1.f / 256.f);
        float var = sq_ * (1.f / 256.f) - mu * mu;
        rs2[r] = mu;
        rq2[r] = rsqrtf(var + 1e-5f);
    }
#pragma unroll
    for (int nf = 0; nf < 4; ++nf) {
        int n = wn * 64 + nf * 16 + lq;
        float gn = g2[n], bn_ = be2[n];
#pragma unroll
        for (int r = 0; r < 4; ++r) {
            int row = hi * 4 + r;
            out[(size_t)(bm + row) * 256 + n] =
                (vv[nf][r] - rs2[r]) * rq2[r] * gn + bn_;
        }
    }
}

extern "C" void kernel_launch(void* const* d_in, const int* in_sizes, int n_in,
                              void* d_out, int out_size, void* d_ws, size_t ws_size,
                              hipStream_t stream) {
    const float* x          = (const float*)d_in[0];
    const float* theta_attn = (const float*)d_in[1];
    const float* w_in       = (const float*)d_in[2];
    const float* b_in       = (const float*)d_in[3];
    const float* w_out      = (const float*)d_in[4];
    const float* b_out      = (const float*)d_in[5];
    const float* w_comb     = (const float*)d_in[6];
    const float* b_comb     = (const float*)d_in[7];
    const float* g1         = (const float*)d_in[8];
    const float* be1        = (const float*)d_in[9];
    const float* g2         = (const float*)d_in[10];
    const float* be2        = (const float*)d_in[11];
    const float* w_ip       = (const float*)d_in[12];
    const float* b_ip       = (const float*)d_in[13];
    const float* theta_ffn  = (const float*)d_in[14];
    const float* w1         = (const float*)d_in[15];
    const float* b1         = (const float*)d_in[16];
    const float* w2         = (const float*)d_in[17];
    const float* b2         = (const float*)d_in[18];
    float* out = (float*)d_out;

    char* wsb = (char*)d_ws;
    ushort* qkv_bf  = (ushort*)(wsb);                         // [0, 6MB)
    ushort* ctx_bf  = (ushort*)(wsb + (6u << 20));            // [6, 8MB)
    ushort* weff_bf = (ushort*)(wsb + (8u << 20));            // 128KB
    ushort* w2_bf   = (ushort*)(wsb + (8u << 20) + 131072);   // 512KB
    float*  beff    = (float*)(wsb + (9u << 20));             // 1KB

    d1_kernel<<<904, 256, 0, stream>>>(x, theta_attn, w_in, b_in, w_out, w_comb,
                                       b_out, b_comb, w2, qkv_bf, weff_bf, beff, w2_bf);
    attn_mfma_kernel<<<dim3(S_ / 256, H_, B_), 512, 0, stream>>>(qkv_bf, ctx_bf);
    d34_kernel<<<M_ / 16, 256, 0, stream>>>(ctx_bf, weff_bf, beff, x, g1, be1,
                                            w_ip, b_ip, theta_ffn, w1, b1,
                                            w2_bf, b2, g2, be2, out);
}